// Round 27
// baseline (843.715 us; speedup 1.0000x reference)
//
#include <hip/hip_runtime.h>
#include <math.h>

#define NB 8
#define NP 2048
#define KNN 20
#define CSTR 520          // padded row stride of the cat feature buffer (floats)
#define NEG 0.2f
// padded column layout: [x:0..3)[pad:3][x1:4..68)[x2:68..132)[x3:132..260)[x4:260..516)

__device__ __forceinline__ float leaky(float x) { return x >= 0.0f ? x : NEG * x; }

typedef __attribute__((ext_vector_type(8))) short bf16x8;
typedef __attribute__((ext_vector_type(4))) float f32x4;

__device__ __forceinline__ unsigned short f2bf(float f) {
    unsigned u = __float_as_uint(f);
    u += 0x7FFFu + ((u >> 16) & 1u);      // round-to-nearest-even
    return (unsigned short)(u >> 16);
}

// ---------------- transpose x (B,3,N) -> cat[:, :, 0:3], zero pad col 3 ----------------
__global__ void tx_kernel(const float* __restrict__ x, float* __restrict__ cat) {
    int i = blockIdx.x * blockDim.x + threadIdx.x;
    if (i >= NB * NP) return;
    int b = i / NP, n = i % NP;
    float* r = cat + (size_t)i * CSTR;
    r[0] = x[((size_t)b * 3 + 0) * NP + n];
    r[1] = x[((size_t)b * 3 + 1) * NP + n];
    r[2] = x[((size_t)b * 3 + 2) * NP + n];
    r[3] = 0.0f;
    r[516] = 0.f; r[517] = 0.f; r[518] = 0.f; r[519] = 0.f;
}

// ---------------- conv weights W (O, 2*Cin) -> Wyz (PC, 2*O): [Wd | Wc - Wd] ----------------
__global__ void buildWyz(const float* __restrict__ W, float* __restrict__ Wyz,
                         int O, int Cin, int PC) {
    int i = blockIdx.x * blockDim.x + threadIdx.x;
    int N2 = 2 * O;
    if (i >= PC * N2) return;
    int q = i / N2, n = i - q * N2;
    float v = 0.0f;
    if (q != 3) {
        int c = (q < 3) ? q : q - 1;
        if (c < Cin) {
            int o = (n < O) ? n : n - O;
            float wd = W[(size_t)o * (2 * Cin) + c];
            v = (n < O) ? wd : (W[(size_t)o * (2 * Cin) + Cin + c] - wd);
        }
    }
    Wyz[i] = v;
}

// ---------------- W5 (1024, 515) -> padded transposed W5t (520, 1024) ----------------
__global__ void transposeW5(const float* __restrict__ W, float* __restrict__ Wt) {
    int i = blockIdx.x * blockDim.x + threadIdx.x;
    if (i >= 520 * 1024) return;
    int p = i >> 10, o = i & 1023;
    float v = 0.0f;
    if (p < 516 && p != 3) {
        int c = (p < 3) ? p : p - 1;
        v = W[(size_t)o * 515 + c];
    }
    Wt[i] = v;
}

// ---------------- pack W5t into MFMA B-fragment order (bf16, K padded to 544) ----------------
__global__ void packW5B(const float* __restrict__ W5t, unsigned short* __restrict__ W5P) {
    int idx = blockIdx.x * blockDim.x + threadIdx.x;
    if (idx >= 64 * 17 * 64) return;
    int ct = idx / (17 * 64);
    int rem = idx - ct * 17 * 64;
    int ks = rem >> 6, l = rem & 63;
    int col = ct * 16 + (l & 15);
    int kbase = ks * 32 + (l >> 4) * 8;
    unsigned short out[8];
    #pragma unroll
    for (int j = 0; j < 8; ++j) {
        int k = kbase + j;
        out[j] = (k < 520) ? f2bf(W5t[(size_t)k * 1024 + col]) : (unsigned short)0;
    }
    *reinterpret_cast<uint4*>(W5P + (size_t)idx * 8) = *reinterpret_cast<uint4*>(out);
}

// ---------------- pack WYZ4 (260 x 512) into MFMA B-fragment order (bf16, K padded 288) ----------------
__global__ void packW4B(const float* __restrict__ Wyz, unsigned short* __restrict__ W4P) {
    int idx = blockIdx.x * blockDim.x + threadIdx.x;
    if (idx >= 32 * 9 * 64) return;
    int ct = idx / (9 * 64);
    int rem = idx - ct * 9 * 64;
    int ks = rem >> 6, l = rem & 63;
    int col = ct * 16 + (l & 15);
    int kbase = ks * 32 + (l >> 4) * 8;
    unsigned short out[8];
    #pragma unroll
    for (int j = 0; j < 8; ++j) {
        int k = kbase + j;
        out[j] = (k < 260) ? f2bf(Wyz[(size_t)k * 512 + col]) : (unsigned short)0;
    }
    *reinterpret_cast<uint4*>(W4P + (size_t)idx * 8) = *reinterpret_cast<uint4*>(out);
}

// ---------------- squared norms of feature slice (padded C, pad col is zero) ----------------
__global__ void sqnorm_kernel(const float* __restrict__ cat, int off, int C, float* __restrict__ sq) {
    int i = blockIdx.x * blockDim.x + threadIdx.x;
    if (i >= NB * NP) return;
    const float* f = cat + (size_t)i * CSTR + off;
    float s = 0.f;
    for (int c = 0; c < C; c += 4) {
        float4 v = *reinterpret_cast<const float4*>(f + c);
        s += v.x * v.x + v.y * v.y + v.z * v.z + v.w * v.w;
    }
    sq[i] = s;
}

// ---------------- XT4: pack layer-1 points as (x,y,z,sqnorm) — one float4 per point ----------------
__global__ void xt4_kernel(const float* __restrict__ cat, float4* __restrict__ XT4) {
    int i = blockIdx.x * blockDim.x + threadIdx.x;
    if (i >= NB * NP) return;
    const float* r = cat + (size_t)i * CSTR;
    float xx = r[0], yy = r[1], zz = r[2];
    XT4[i] = make_float4(xx, yy, zz, xx * xx + yy * yy + zz * zz);
}

// ---------------- selection core v3: TWO queries per wave, top-2 cache, interleaved chains ----------------
// Each query's semantics identical to v2 (strict > keeps lowest t; ballot lowest-lane = lowest
// global j under contiguous ownership). The two independent butterfly/ballot chains interleave
// in the issue slots -> cross-lane latency hidden.
__device__ __forceinline__ void select_top20_x2(float (&dA)[32], float (&dB)[32],
                                                int jbase, int lane,
                                                int* __restrict__ outA,
                                                int* __restrict__ outB) {
    unsigned selA = 0, selB = 0;
    float m1A = -INFINITY, m2A = -INFINITY, m1B = -INFINITY, m2B = -INFINITY;
    int j1A = 0, j2A = 0, j1B = 0, j2B = 0;
    #pragma unroll
    for (int t = 0; t < 32; ++t) {
        float vA = dA[t], vB = dB[t];
        if (vA > m1A) { m2A = m1A; j2A = j1A; m1A = vA; j1A = t; }
        else if (vA > m2A) { m2A = vA; j2A = t; }
        if (vB > m1B) { m2B = m1B; j2B = j1B; m1B = vB; j1B = t; }
        else if (vB > m2B) { m2B = vB; j2B = t; }
    }
    bool dirtyA = false, dirtyB = false;
    for (int k = 0; k < KNN; ++k) {
        float bvA = m1A, bvB = m1B;
        #pragma unroll
        for (int s = 32; s; s >>= 1) {
            bvA = fmaxf(bvA, __shfl_xor(bvA, s));
            bvB = fmaxf(bvB, __shfl_xor(bvB, s));
        }
        unsigned long long mA = __ballot(m1A == bvA);
        unsigned long long mB = __ballot(m1B == bvB);
        int wlA = __ffsll(mA) - 1, wlB = __ffsll(mB) - 1;
        int bjA = __shfl(jbase + j1A, wlA);
        int bjB = __shfl(jbase + j1B, wlB);
        if (lane == 0) { outA[k] = bjA; outB[k] = bjB; }
        if (lane == wlA) {
            selA |= 1u << j1A;
            if (!dirtyA) { m1A = m2A; j1A = j2A; dirtyA = true; }
            else {
                m1A = -INFINITY; m2A = -INFINITY; j1A = 0; j2A = 0;
                #pragma unroll
                for (int t = 0; t < 32; ++t) {
                    float v = (selA & (1u << t)) ? -INFINITY : dA[t];
                    if (v > m1A) { m2A = m1A; j2A = j1A; m1A = v; j1A = t; }
                    else if (v > m2A) { m2A = v; j2A = t; }
                }
                dirtyA = false;
            }
        }
        if (lane == wlB) {
            selB |= 1u << j1B;
            if (!dirtyB) { m1B = m2B; j1B = j2B; dirtyB = true; }
            else {
                m1B = -INFINITY; m2B = -INFINITY; j1B = 0; j2B = 0;
                #pragma unroll
                for (int t = 0; t < 32; ++t) {
                    float v = (selB & (1u << t)) ? -INFINITY : dB[t];
                    if (v > m1B) { m2B = m1B; j2B = j1B; m1B = v; j1B = t; }
                    else if (v > m2B) { m2B = v; j2B = t; }
                }
                dirtyB = false;
            }
        }
    }
}

// ---------------- layer-1 KNN: one wave per TWO queries, shared candidate loads ----------------
__global__ void __launch_bounds__(256) knn1_kernel(const float4* __restrict__ XT4,
                                                   int* __restrict__ idxout) {
    int wave = threadIdx.x >> 6, lane = threadIdx.x & 63;
    int q0 = blockIdx.x * 8 + wave * 2;     // two queries per wave, same batch
    int b = q0 >> 11, n0 = q0 & (NP - 1), n1 = n0 + 1;
    const float4* base = XT4 + (size_t)b * NP;
    float4 qa = base[n0];                   // wave-uniform -> broadcast
    float4 qb = base[n1];
    float dA[32], dB[32];
    #pragma unroll
    for (int t = 0; t < 32; ++t) {
        float4 v = base[lane * 32 + t];     // shared candidate load for both queries
        dA[t] = 2.f * (qa.x * v.x + qa.y * v.y + qa.z * v.z) - qa.w - v.w;
        dB[t] = 2.f * (qb.x * v.x + qb.y * v.y + qb.z * v.z) - qb.w - v.w;
    }
    select_top20_x2(dA, dB, lane * 32, lane,
                    idxout + (size_t)q0 * KNN, idxout + (size_t)(q0 + 1) * KNN);
}

// ---------------- XT: slice transpose cat[b][n][off+c] -> XT[bl][c][n] ----------------
template <int K>
__global__ void __launch_bounds__(256) xt_kernel(const float* __restrict__ cat, int off,
                                                 float* __restrict__ XT, int b0) {
    __shared__ float lds[64][K + 1];
    int bl = blockIdx.x;
    int b = b0 + bl;
    int n0 = blockIdx.y * 64;
    const float* src = cat + ((size_t)(b * NP + n0)) * CSTR + off;
    for (int e = threadIdx.x; e < 64 * (K / 4); e += 256) {
        int r = e / (K / 4), cg = e - r * (K / 4);
        float4 v = *reinterpret_cast<const float4*>(src + (size_t)r * CSTR + 4 * cg);
        lds[r][4 * cg + 0] = v.x; lds[r][4 * cg + 1] = v.y;
        lds[r][4 * cg + 2] = v.z; lds[r][4 * cg + 3] = v.w;
    }
    __syncthreads();
    float* dst = XT + (size_t)bl * K * NP;
    for (int e = threadIdx.x; e < 64 * K; e += 256) {
        int c = e >> 6, tn = e & 63;
        dst[(size_t)c * NP + n0 + tn] = lds[tn][c];
    }
}

// ---------------- SYMMETRIC distance GEMM: 64x64 tiles, upper-triangular pairs + mirror ----------------
template <int K>
__global__ void __launch_bounds__(256, 2)
distsym_kernel(const float* __restrict__ cat, int off,
               const float* __restrict__ sq,
               const float* __restrict__ XT,
               float* __restrict__ D, int b0) {
    constexpr int KP = K + 4;
    __shared__ float Arows[64][KP];          // K=128: 33.8 KB
    const int T = NP / 64;                   // 32 tiles
    const int NPAIR = T * (T + 1) / 2;       // 528
    int bid = blockIdx.x;
    int bl = bid / NPAIR;
    int p = bid - bl * NPAIR;
    int ti = 0, rem = p;
    while (rem >= T - ti) { rem -= T - ti; ++ti; }
    int tj = ti + rem;
    int b = b0 + bl;
    int rowbase = ti * 64, colbase = tj * 64;
    const float* src = cat + ((size_t)(b * NP + rowbase)) * CSTR + off;
    for (int e = threadIdx.x; e < 64 * (K / 4); e += 256) {
        int r = e / (K / 4), cg = e - r * (K / 4);
        *reinterpret_cast<float4*>(&Arows[r][4 * cg]) =
            *reinterpret_cast<const float4*>(src + (size_t)r * CSTR + 4 * cg);
    }
    __syncthreads();
    int tx = threadIdx.x & 15, ty = threadIdx.x >> 4;
    int r0 = ty * 4, c0 = tx * 4;
    int col = colbase + c0;
    const float* Wb = XT + (size_t)bl * K * NP + col;
    float acc[4][4];
    #pragma unroll
    for (int i = 0; i < 4; ++i)
        #pragma unroll
        for (int j = 0; j < 4; ++j) acc[i][j] = 0.f;
    float4 wbufA[4], wbufB[4];
    auto ldw = [&](float4 (&dst)[4], int cc) {
        dst[0] = *reinterpret_cast<const float4*>(Wb + (size_t)(cc + 0) * NP);
        dst[1] = *reinterpret_cast<const float4*>(Wb + (size_t)(cc + 1) * NP);
        dst[2] = *reinterpret_cast<const float4*>(Wb + (size_t)(cc + 2) * NP);
        dst[3] = *reinterpret_cast<const float4*>(Wb + (size_t)(cc + 3) * NP);
    };
    auto fmad = [&](float4 (&wv)[4], int cc) {
        #pragma unroll
        for (int i = 0; i < 4; ++i) {
            float4 a = *reinterpret_cast<const float4*>(&Arows[r0 + i][cc]);
            acc[i][0] += a.x * wv[0].x + a.y * wv[1].x + a.z * wv[2].x + a.w * wv[3].x;
            acc[i][1] += a.x * wv[0].y + a.y * wv[1].y + a.z * wv[2].y + a.w * wv[3].y;
            acc[i][2] += a.x * wv[0].z + a.y * wv[1].z + a.z * wv[2].z + a.w * wv[3].z;
            acc[i][3] += a.x * wv[0].w + a.y * wv[1].w + a.z * wv[2].w + a.w * wv[3].w;
        }
    };
    ldw(wbufA, 0);
    for (int c = 0; c < K; c += 8) {
        if (c + 4 < K) ldw(wbufB, c + 4);
        fmad(wbufA, c);
        if (c + 8 < K) ldw(wbufA, c + 8);
        if (c + 4 < K) fmad(wbufB, c + 4);
    }
    float4 sqc = *reinterpret_cast<const float4*>(&sq[(size_t)b * NP + col]);
    float4 dv[4];
    #pragma unroll
    for (int i = 0; i < 4; ++i) {
        float sqr = sq[(size_t)b * NP + rowbase + r0 + i];
        dv[i] = make_float4(2.f * acc[i][0] - sqr - sqc.x, 2.f * acc[i][1] - sqr - sqc.y,
                            2.f * acc[i][2] - sqr - sqc.z, 2.f * acc[i][3] - sqr - sqc.w);
        *reinterpret_cast<float4*>(&D[((size_t)bl * NP + rowbase + r0 + i) * NP + col]) = dv[i];
    }
    if (ti != tj) {   // mirror: D[col+j][rowbase+r0..r0+3]
        float4 mv0 = make_float4(dv[0].x, dv[1].x, dv[2].x, dv[3].x);
        float4 mv1 = make_float4(dv[0].y, dv[1].y, dv[2].y, dv[3].y);
        float4 mv2 = make_float4(dv[0].z, dv[1].z, dv[2].z, dv[3].z);
        float4 mv3 = make_float4(dv[0].w, dv[1].w, dv[2].w, dv[3].w);
        size_t mbase = ((size_t)bl * NP + colbase + c0);
        int mcol = rowbase + r0;
        *reinterpret_cast<float4*>(&D[(mbase + 0) * NP + mcol]) = mv0;
        *reinterpret_cast<float4*>(&D[(mbase + 1) * NP + mcol]) = mv1;
        *reinterpret_cast<float4*>(&D[(mbase + 2) * NP + mcol]) = mv2;
        *reinterpret_cast<float4*>(&D[(mbase + 3) * NP + mcol]) = mv3;
    }
}

// ---------------- top-k v6: two rows per wave, top-2 cache selection ----------------
__global__ void __launch_bounds__(256) topk_kernel(const float* __restrict__ D,
                                                   int* __restrict__ idxout, int b0) {
    int wave = threadIdx.x >> 6, lane = threadIdx.x & 63;
    int ql0 = blockIdx.x * 8 + wave * 2;
    const float* drow0 = D + (size_t)ql0 * NP + lane * 32;
    const float* drow1 = drow0 + NP;
    float dA[32], dB[32];
    #pragma unroll
    for (int t8 = 0; t8 < 8; ++t8) {
        float4 v0 = *reinterpret_cast<const float4*>(drow0 + t8 * 4);
        float4 v1 = *reinterpret_cast<const float4*>(drow1 + t8 * 4);
        dA[t8 * 4 + 0] = v0.x; dA[t8 * 4 + 1] = v0.y;
        dA[t8 * 4 + 2] = v0.z; dA[t8 * 4 + 3] = v0.w;
        dB[t8 * 4 + 0] = v1.x; dB[t8 * 4 + 1] = v1.y;
        dB[t8 * 4 + 2] = v1.z; dB[t8 * 4 + 3] = v1.w;
    }
    size_t q = (size_t)b0 * NP + ql0;
    select_top20_x2(dA, dB, lane * 32, lane, idxout + q * KNN, idxout + (q + 1) * KNN);
}

// ---------------- YZ GEMM: NO cols/thread + double-buffered weight prefetch ----------------
template <int K, int NT, int NO>
__global__ void __launch_bounds__(NT, 2)
gemm_yz_kernel(const float* __restrict__ cat, int off,
               const float* __restrict__ W, int N2,
               float* __restrict__ YZ) {
    __shared__ float rows[16][K];
    int col = (blockIdx.y * NT + threadIdx.x) * NO;
    const float* src = cat + (size_t)blockIdx.x * 16 * CSTR + off;
    for (int e = threadIdx.x; e < 16 * (K / 4); e += NT) {
        int r = e / (K / 4), cg = e - r * (K / 4);
        *reinterpret_cast<float4*>(&rows[r][4 * cg]) =
            *reinterpret_cast<const float4*>(src + (size_t)r * CSTR + 4 * cg);
    }
    __syncthreads();
    float acc[16][NO];
    #pragma unroll
    for (int r = 0; r < 16; ++r)
        #pragma unroll
        for (int j = 0; j < NO; ++j) acc[r][j] = 0.f;
    auto ldw = [&](float (&buf)[4][NO], int cc) {
        #pragma unroll
        for (int i = 0; i < 4; ++i) {
            if constexpr (NO == 4) {
                float4 wq = *reinterpret_cast<const float4*>(&W[(size_t)(cc + i) * N2 + col]);
                buf[i][0] = wq.x; buf[i][1] = wq.y; buf[i][2] = wq.z; buf[i][3] = wq.w;
            } else if constexpr (NO == 2) {
                float2 wq = *reinterpret_cast<const float2*>(&W[(size_t)(cc + i) * N2 + col]);
                buf[i][0] = wq.x; buf[i][1] = wq.y;
            } else {
                buf[i][0] = W[(size_t)(cc + i) * N2 + col];
            }
        }
    };
    auto fmag = [&](float (&wv)[4][NO], int cc) {
        #pragma unroll
        for (int r = 0; r < 16; ++r) {
            float4 rv = *reinterpret_cast<const float4*>(&rows[r][cc]);
            #pragma unroll
            for (int j = 0; j < NO; ++j)
                acc[r][j] += rv.x * wv[0][j] + rv.y * wv[1][j] + rv.z * wv[2][j] + rv.w * wv[3][j];
        }
    };
    float wva[4][NO], wvb[4][NO];
    ldw(wva, 0);
    for (int c = 0; c < K; c += 8) {
        if (c + 4 < K) ldw(wvb, c + 4);
        fmag(wva, c);
        if (c + 8 < K) ldw(wva, c + 8);
        if (c + 4 < K) fmag(wvb, c + 4);
    }
    #pragma unroll
    for (int r = 0; r < 16; ++r) {
        float* dst = YZ + ((size_t)blockIdx.x * 16 + r) * N2 + col;
        if constexpr (NO == 4) {
            *reinterpret_cast<float4*>(dst) = make_float4(acc[r][0], acc[r][1], acc[r][2], acc[r][3]);
        } else if constexpr (NO == 2) {
            *reinterpret_cast<float2*>(dst) = make_float2(acc[r][0], acc[r][1]);
        } else {
            dst[0] = acc[r][0];
        }
    }
}

// ---------------- YZ layer-4 GEMM via bf16 MFMA (x4 feeds only the bf16 pool, no KNN) ----------------
__global__ void __launch_bounds__(256, 2)
yz4_mfma(const float* __restrict__ cat, const unsigned short* __restrict__ W4P,
         float* __restrict__ YZ) {
    __shared__ unsigned short Alds[32][296];   // 18.9 KB
    int chunk = blockIdx.x;          // 512 chunks of 32 global rows
    int cg = blockIdx.y;             // 2 col groups of 256
    for (int e = threadIdx.x; e < 32 * 72; e += 256) {
        int r = e / 72, gq = e - r * 72;
        int k = gq * 4;
        unsigned short o0 = 0, o1 = 0, o2 = 0, o3 = 0;
        if (k < 260) {
            float4 v = *reinterpret_cast<const float4*>(
                &cat[((size_t)chunk * 32 + r) * CSTR + k]);
            o0 = f2bf(v.x); o1 = f2bf(v.y); o2 = f2bf(v.z); o3 = f2bf(v.w);
        }
        *reinterpret_cast<ushort4*>(&Alds[r][k]) = make_ushort4(o0, o1, o2, o3);
    }
    __syncthreads();
    int l = threadIdx.x & 63, w = threadIdx.x >> 6;
    int ct0 = cg * 16 + w * 4;       // 32 col tiles of 16
    f32x4 acc[2][4];
    #pragma unroll
    for (int rt = 0; rt < 2; ++rt)
        #pragma unroll
        for (int t = 0; t < 4; ++t) acc[rt][t] = (f32x4){0.f, 0.f, 0.f, 0.f};
    int arow0 = (l & 15), arow1 = 16 + (l & 15);
    int koff = (l >> 4) * 8;
    for (int ks = 0; ks < 9; ++ks) {
        bf16x8 a0 = *reinterpret_cast<const bf16x8*>(&Alds[arow0][ks * 32 + koff]);
        bf16x8 a1 = *reinterpret_cast<const bf16x8*>(&Alds[arow1][ks * 32 + koff]);
        #pragma unroll
        for (int t = 0; t < 4; ++t) {
            bf16x8 bfr = *reinterpret_cast<const bf16x8*>(
                W4P + (((size_t)(ct0 + t) * 9 + ks) * 64 + l) * 8);
            acc[0][t] = __builtin_amdgcn_mfma_f32_16x16x32_bf16(a0, bfr, acc[0][t], 0, 0, 0);
            acc[1][t] = __builtin_amdgcn_mfma_f32_16x16x32_bf16(a1, bfr, acc[1][t], 0, 0, 0);
        }
    }
    #pragma unroll
    for (int rt = 0; rt < 2; ++rt)
        #pragma unroll
        for (int t = 0; t < 4; ++t) {
            int col = (ct0 + t) * 16 + (l & 15);
            #pragma unroll
            for (int jj = 0; jj < 4; ++jj) {
                int row = chunk * 32 + rt * 16 + (l >> 4) * 4 + jj;
                YZ[(size_t)row * 512 + col] = acc[rt][t][jj];
            }
        }
}

// ---------------- combine: out[p][o] = max_k leaky((Y[j_k][o] + Z[p][o])*s + b) ----------------
template <int O>
__global__ void __launch_bounds__(256) combine_kernel(const float* __restrict__ YZ, int N2,
                                                      const int* __restrict__ idx,
                                                      const float* __restrict__ g,
                                                      const float* __restrict__ bias,
                                                      float* __restrict__ cat, int outOff) {
    constexpr int PPB = 256 / O;
    int sub = threadIdx.x / O, o = threadIdx.x % O;
    int p = blockIdx.x * PPB + sub;
    int bbase = p & ~(NP - 1);
    const float bns = 1.0f / sqrtf(1.0f + 1e-5f);
    float s = g[o] * bns, bo = bias[o];
    float z = YZ[(size_t)p * N2 + O + o];
    int js[KNN];
    #pragma unroll
    for (int k = 0; k < KNN; ++k) js[k] = idx[(size_t)p * KNN + k];
    float m = -INFINITY;
    #pragma unroll
    for (int k = 0; k < KNN; ++k) {
        float y = YZ[(size_t)(bbase + js[k]) * N2 + o];
        m = fmaxf(m, leaky((y + z) * s + bo));
    }
    cat[(size_t)p * CSTR + outOff + o] = m;
}

// ---------------- fused W5 matmul + pool, v12: bf16 MFMA 16x16x32 (proven r20) ----------------
__global__ void __launch_bounds__(256, 2)
pool_w5_mfma(const float* __restrict__ cat, const unsigned short* __restrict__ W5P,
             const float* __restrict__ g5, const float* __restrict__ b5,
             float* __restrict__ pmax, float* __restrict__ psum) {
    __shared__ unsigned short Alds[32][552];   // 35.3 KB
    int b = blockIdx.x >> 6, nb = blockIdx.x & 63;   // 64 chunks of 32 rows
    int cg = blockIdx.y;                              // 4 col groups of 256
    for (int e = threadIdx.x; e < 32 * 136; e += 256) {
        int r = e / 136, gq = e - r * 136;
        int k = gq * 4;
        unsigned short o0 = 0, o1 = 0, o2 = 0, o3 = 0;
        if (k < 520) {
            float4 v = *reinterpret_cast<const float4*>(
                &cat[((size_t)b * NP + nb * 32 + r) * CSTR + k]);
            o0 = f2bf(v.x); o1 = f2bf(v.y); o2 = f2bf(v.z); o3 = f2bf(v.w);
        }
        *reinterpret_cast<ushort4*>(&Alds[r][k]) = make_ushort4(o0, o1, o2, o3);
    }
    __syncthreads();
    int l = threadIdx.x & 63, w = threadIdx.x >> 6;
    int ct0 = cg * 16 + w * 4;          // global col-tile base (64 tiles of 16)
    f32x4 acc[2][4];
    #pragma unroll
    for (int rt = 0; rt < 2; ++rt)
        #pragma unroll
        for (int t = 0; t < 4; ++t) acc[rt][t] = (f32x4){0.f, 0.f, 0.f, 0.f};
    int arow0 = (l & 15), arow1 = 16 + (l & 15);
    int koff = (l >> 4) * 8;
    for (int ks = 0; ks < 17; ++ks) {
        bf16x8 a0 = *reinterpret_cast<const bf16x8*>(&Alds[arow0][ks * 32 + koff]);
        bf16x8 a1 = *reinterpret_cast<const bf16x8*>(&Alds[arow1][ks * 32 + koff]);
        #pragma unroll
        for (int t = 0; t < 4; ++t) {
            bf16x8 bfr = *reinterpret_cast<const bf16x8*>(
                W5P + (((size_t)(ct0 + t) * 17 + ks) * 64 + l) * 8);
            acc[0][t] = __builtin_amdgcn_mfma_f32_16x16x32_bf16(a0, bfr, acc[0][t], 0, 0, 0);
            acc[1][t] = __builtin_amdgcn_mfma_f32_16x16x32_bf16(a1, bfr, acc[1][t], 0, 0, 0);
        }
    }
    const float bns = 1.0f / sqrtf(1.0f + 1e-5f);
    #pragma unroll
    for (int t = 0; t < 4; ++t) {
        int col = (ct0 + t) * 16 + (l & 15);
        float gs = g5[col] * bns, bo = b5[col];
        float vmax = -INFINITY, vsum = 0.f;
        #pragma unroll
        for (int rt = 0; rt < 2; ++rt)
            #pragma unroll
            for (int jj = 0; jj < 4; ++jj) {
                float v = leaky(acc[rt][t][jj] * gs + bo);
                vmax = fmaxf(vmax, v); vsum += v;
            }
        vmax = fmaxf(vmax, __shfl_xor(vmax, 16)); vsum += __shfl_xor(vsum, 16);
        vmax = fmaxf(vmax, __shfl_xor(vmax, 32)); vsum += __shfl_xor(vsum, 32);
        if (l < 16) {
            pmax[((size_t)b * 64 + nb) * 1024 + col] = vmax;
            psum[((size_t)b * 64 + nb) * 1024 + col] = vsum;
        }
    }
}

__global__ void pool_reduce_kernel(const float* __restrict__ pmax, const float* __restrict__ psum,
                                   float* __restrict__ f0) {
    int i = blockIdx.x * blockDim.x + threadIdx.x;
    if (i >= NB * 1024) return;
    int b = i >> 10, o = i & 1023;
    float m = -INFINITY, sm = 0.f;
    for (int nc = 0; nc < 64; ++nc) {
        m = fmaxf(m, pmax[((size_t)b * 64 + nc) * 1024 + o]);
        sm += psum[((size_t)b * 64 + nc) * 1024 + o];
    }
    f0[(size_t)b * 2048 + o] = m;
    f0[(size_t)b * 2048 + 1024 + o] = sm * (1.0f / 2048.0f);
}

// ---------------- dense: one thread per (b, o), float4 dot ----------------
__global__ void dense_kernel(const float* __restrict__ in, const float* __restrict__ W,
                             const float* __restrict__ bl, const float* __restrict__ g,
                             const float* __restrict__ bb, float* __restrict__ out,
                             int In, int Out, int act) {
    int i = blockIdx.x * blockDim.x + threadIdx.x;
    if (i >= NB * Out) return;
    int b = i / Out, o = i - b * Out;
    const float* w = W + (size_t)o * In;
    const float* xv = in + (size_t)b * In;
    float acc = 0.f;
    for (int c = 0; c < In; c += 4) {
        float4 a = *reinterpret_cast<const float4*>(&xv[c]);
        float4 v = *reinterpret_cast<const float4*>(&w[c]);
        acc += a.x * v.x + a.y * v.y + a.z * v.z + a.w * v.w;
    }
    acc += bl[o];
    if (act) {
        const float bns = 1.0f / sqrtf(1.0f + 1e-5f);
        acc = leaky(acc * (g[o] * bns) + bb[o]);
    }
    out[i] = acc;
}

extern "C" void kernel_launch(void* const* d_in, const int* in_sizes, int n_in,
                              void* d_out, int out_size, void* d_ws, size_t ws_size,
                              hipStream_t stream) {
    const float* x   = (const float*)d_in[0];
    const float* W1  = (const float*)d_in[2];
    const float* W2  = (const float*)d_in[3];
    const float* W3  = (const float*)d_in[4];
    const float* W4  = (const float*)d_in[5];
    const float* W5  = (const float*)d_in[6];
    const float* Wl1 = (const float*)d_in[7];
    const float* bl1 = (const float*)d_in[8];
    const float* Wl2 = (const float*)d_in[9];
    const float* bl2 = (const float*)d_in[10];
    const float* Wl3 = (const float*)d_in[11];
    const float* bl3 = (const float*)d_in[12];
    const float* g1 = (const float*)d_in[13]; const float* b1 = (const float*)d_in[14];
    const float* g2 = (const float*)d_in[15]; const float* b2 = (const float*)d_in[16];
    const float* g3 = (const float*)d_in[17]; const float* b3 = (const float*)d_in[18];
    const float* g4 = (const float*)d_in[19]; const float* b4 = (const float*)d_in[20];
    const float* g5 = (const float*)d_in[21]; const float* b5 = (const float*)d_in[22];
    const float* g6 = (const float*)d_in[23]; const float* bb6 = (const float*)d_in[24];
    const float* g7 = (const float*)d_in[25]; const float* bb7 = (const float*)d_in[26];

    float* ws = (float*)d_ws;
    size_t off = 0;
    float* CAT = ws + off; off += (size_t)NB * NP * CSTR;
    float* SQ  = ws + off; off += NB * NP;
    int*   IDX = (int*)(ws + off); off += (size_t)NB * NP * KNN;
    float* WYZ1 = ws + off; off += 4 * 128;
    float* WYZ2 = ws + off; off += 68 * 128;
    float* WYZ3 = ws + off; off += 132 * 256;
    float* WYZ4 = ws + off; off += 260 * 512;
    float* W5T = ws + off; off += 520 * 1024;
    unsigned short* W5P = (unsigned short*)(ws + off); off += 64 * 17 * 64 * 8 / 2;
    unsigned short* W4P = (unsigned short*)(ws + off); off += 32 * 9 * 64 * 8 / 2;
    float* BIG = ws + off;                    // shared region: DMAT+XT | XT4 | YZ | pool buffers
    size_t wsfl = ws_size / 4;
    size_t avail = (wsfl > off) ? (wsfl - off) : 0;
    const size_t yzneed = (size_t)NB * NP * 512;
    int G = 1;
    for (int g = 8; g >= 1; g >>= 1) {
        size_t need = (size_t)g * NP * 2048 + (size_t)g * 128 * NP;   // DMAT + XT(K<=128)
        size_t big = (need > yzneed) ? need : yzneed;
        if (big <= avail) { G = g; break; }
    }
    float* DMAT = BIG;
    float* XT   = BIG + (size_t)G * NP * 2048;
    float4* XT4 = (float4*)BIG;               // layer-1 point pack (256 KB)
    float* YZ   = BIG;
    float* PMAX = BIG;
    float* PSUM = PMAX + (size_t)NB * 64 * 1024;
    float* F0 = PSUM + (size_t)NB * 64 * 1024;
    float* F1 = F0 + NB * 2048;
    float* F2 = F1 + NB * 512;
    (void)in_sizes; (void)n_in; (void)out_size;

    dim3 b256(256);
    const int M16 = NB * NP / 16;   // 1024 row-blocks
    const int NPAIR = (NP / 64) * (NP / 64 + 1) / 2;   // 528

    tx_kernel<<<(NB * NP + 255) / 256, b256, 0, stream>>>(x, CAT);
    buildWyz<<<(4 * 128 + 255) / 256, b256, 0, stream>>>(W1, WYZ1, 64, 3, 4);
    buildWyz<<<(68 * 128 + 255) / 256, b256, 0, stream>>>(W2, WYZ2, 64, 67, 68);
    buildWyz<<<(132 * 256 + 255) / 256, b256, 0, stream>>>(W3, WYZ3, 128, 131, 132);
    buildWyz<<<(260 * 512 + 255) / 256, b256, 0, stream>>>(W4, WYZ4, 256, 259, 260);
    transposeW5<<<(520 * 1024 + 255) / 256, b256, 0, stream>>>(W5, W5T);
    packW5B<<<(64 * 17 * 64 + 255) / 256, b256, 0, stream>>>(W5T, W5P);
    packW4B<<<(32 * 9 * 64 + 255) / 256, b256, 0, stream>>>(WYZ4, W4P);

#define RUN_KNN(KK, OFFC)                                                                   \
    do {                                                                                    \
        sqnorm_kernel<<<(NB * NP + 255) / 256, b256, 0, stream>>>(CAT, OFFC, KK, SQ);       \
        for (int b0 = 0; b0 < NB; b0 += G) {                                                \
            xt_kernel<KK><<<dim3(G, NP / 64), b256, 0, stream>>>(CAT, OFFC, XT, b0);        \
            distsym_kernel<KK><<<G * NPAIR, b256, 0, stream>>>(CAT, OFFC, SQ, XT,           \
                                                               DMAT, b0);                   \
            topk_kernel<<<G * NP / 8, b256, 0, stream>>>(DMAT, IDX, b0);                    \
        }                                                                                   \
    } while (0)

    // layer 1: register-distance KNN (zero LDS), two queries per wave
    xt4_kernel<<<(NB * NP + 255) / 256, b256, 0, stream>>>(CAT, XT4);
    knn1_kernel<<<NB * NP / 8, b256, 0, stream>>>(XT4, IDX);
    gemm_yz_kernel<4, 128, 1><<<dim3(M16, 1), 128, 0, stream>>>(CAT, 0, WYZ1, 128, YZ);
    combine_kernel<64><<<NB * NP / 4, b256, 0, stream>>>(YZ, 128, IDX, g1, b1, CAT, 4);
    // layer 2
    RUN_KNN(64, 4);
    gemm_yz_kernel<68, 128, 1><<<dim3(M16, 1), 128, 0, stream>>>(CAT, 0, WYZ2, 128, YZ);
    combine_kernel<64><<<NB * NP / 4, b256, 0, stream>>>(YZ, 128, IDX, g2, b2, CAT, 68);
    // layer 3
    RUN_KNN(64, 68);
    gemm_yz_kernel<132, 128, 2><<<dim3(M16, 1), 128, 0, stream>>>(CAT, 0, WYZ3, 256, YZ);
    combine_kernel<128><<<NB * NP / 2, b256, 0, stream>>>(YZ, 256, IDX, g3, b3, CAT, 132);
    // layer 4: KNN exact f32 (symmetric); YZ GEMM via bf16 MFMA
    RUN_KNN(128, 132);
    yz4_mfma<<<dim3(NB * NP / 32, 2), b256, 0, stream>>>(CAT, W4P, YZ);
    combine_kernel<256><<<NB * NP, b256, 0, stream>>>(YZ, 512, IDX, g4, b4, CAT, 260);
#undef RUN_KNN

    // W5 (bf16 MFMA) + bn + leaky + global max/mean pool
    pool_w5_mfma<<<dim3(NB * 64, 4), b256, 0, stream>>>(CAT, W5P, g5, b5, PMAX, PSUM);
    pool_reduce_kernel<<<(NB * 1024 + 255) / 256, b256, 0, stream>>>(PMAX, PSUM, F0);

    // MLP head
    dense_kernel<<<(NB * 512 + 255) / 256, b256, 0, stream>>>(F0, Wl1, bl1, g6, bb6, F1, 2048, 512, 1);
    dense_kernel<<<(NB * 256 + 255) / 256, b256, 0, stream>>>(F1, Wl2, bl2, g7, bb7, F2, 512, 256, 1);
    dense_kernel<<<(NB * 40 + 255) / 256, b256, 0, stream>>>(F2, Wl3, bl3, nullptr, nullptr,
                                                             (float*)d_out, 256, 40, 0);
}

// Round 28
// 802.117 us; speedup vs baseline: 1.0519x; 1.0519x over previous
//
#include <hip/hip_runtime.h>
#include <math.h>

#define NB 8
#define NP 2048
#define KNN 20
#define CSTR 520          // padded row stride of the cat feature buffer (floats)
#define NEG 0.2f
// padded column layout: [x:0..3)[pad:3][x1:4..68)[x2:68..132)[x3:132..260)[x4:260..516)

__device__ __forceinline__ float leaky(float x) { return x >= 0.0f ? x : NEG * x; }

typedef __attribute__((ext_vector_type(8))) short bf16x8;
typedef __attribute__((ext_vector_type(4))) float f32x4;

__device__ __forceinline__ unsigned short f2bf(float f) {
    unsigned u = __float_as_uint(f);
    u += 0x7FFFu + ((u >> 16) & 1u);      // round-to-nearest-even
    return (unsigned short)(u >> 16);
}

// ---------------- transpose x (B,3,N) -> cat[:, :, 0:3], zero pad col 3 ----------------
__global__ void tx_kernel(const float* __restrict__ x, float* __restrict__ cat) {
    int i = blockIdx.x * blockDim.x + threadIdx.x;
    if (i >= NB * NP) return;
    int b = i / NP, n = i % NP;
    float* r = cat + (size_t)i * CSTR;
    r[0] = x[((size_t)b * 3 + 0) * NP + n];
    r[1] = x[((size_t)b * 3 + 1) * NP + n];
    r[2] = x[((size_t)b * 3 + 2) * NP + n];
    r[3] = 0.0f;
    r[516] = 0.f; r[517] = 0.f; r[518] = 0.f; r[519] = 0.f;
}

// ---------------- conv weights W (O, 2*Cin) -> Wyz (PC, 2*O): [Wd | Wc - Wd] ----------------
__global__ void buildWyz(const float* __restrict__ W, float* __restrict__ Wyz,
                         int O, int Cin, int PC) {
    int i = blockIdx.x * blockDim.x + threadIdx.x;
    int N2 = 2 * O;
    if (i >= PC * N2) return;
    int q = i / N2, n = i - q * N2;
    float v = 0.0f;
    if (q != 3) {
        int c = (q < 3) ? q : q - 1;
        if (c < Cin) {
            int o = (n < O) ? n : n - O;
            float wd = W[(size_t)o * (2 * Cin) + c];
            v = (n < O) ? wd : (W[(size_t)o * (2 * Cin) + Cin + c] - wd);
        }
    }
    Wyz[i] = v;
}

// ---------------- W5 (1024, 515) -> padded transposed W5t (520, 1024) ----------------
__global__ void transposeW5(const float* __restrict__ W, float* __restrict__ Wt) {
    int i = blockIdx.x * blockDim.x + threadIdx.x;
    if (i >= 520 * 1024) return;
    int p = i >> 10, o = i & 1023;
    float v = 0.0f;
    if (p < 516 && p != 3) {
        int c = (p < 3) ? p : p - 1;
        v = W[(size_t)o * 515 + c];
    }
    Wt[i] = v;
}

// ---------------- pack W5t into MFMA B-fragment order (bf16, K padded to 544) ----------------
__global__ void packW5B(const float* __restrict__ W5t, unsigned short* __restrict__ W5P) {
    int idx = blockIdx.x * blockDim.x + threadIdx.x;
    if (idx >= 64 * 17 * 64) return;
    int ct = idx / (17 * 64);
    int rem = idx - ct * 17 * 64;
    int ks = rem >> 6, l = rem & 63;
    int col = ct * 16 + (l & 15);
    int kbase = ks * 32 + (l >> 4) * 8;
    unsigned short out[8];
    #pragma unroll
    for (int j = 0; j < 8; ++j) {
        int k = kbase + j;
        out[j] = (k < 520) ? f2bf(W5t[(size_t)k * 1024 + col]) : (unsigned short)0;
    }
    *reinterpret_cast<uint4*>(W5P + (size_t)idx * 8) = *reinterpret_cast<uint4*>(out);
}

// ---------------- pack WYZ4 (260 x 512) into MFMA B-fragment order (bf16, K padded 288) ----------------
__global__ void packW4B(const float* __restrict__ Wyz, unsigned short* __restrict__ W4P) {
    int idx = blockIdx.x * blockDim.x + threadIdx.x;
    if (idx >= 32 * 9 * 64) return;
    int ct = idx / (9 * 64);
    int rem = idx - ct * 9 * 64;
    int ks = rem >> 6, l = rem & 63;
    int col = ct * 16 + (l & 15);
    int kbase = ks * 32 + (l >> 4) * 8;
    unsigned short out[8];
    #pragma unroll
    for (int j = 0; j < 8; ++j) {
        int k = kbase + j;
        out[j] = (k < 260) ? f2bf(Wyz[(size_t)k * 512 + col]) : (unsigned short)0;
    }
    *reinterpret_cast<uint4*>(W4P + (size_t)idx * 8) = *reinterpret_cast<uint4*>(out);
}

// ---------------- squared norms of feature slice (padded C, pad col is zero) ----------------
__global__ void sqnorm_kernel(const float* __restrict__ cat, int off, int C, float* __restrict__ sq) {
    int i = blockIdx.x * blockDim.x + threadIdx.x;
    if (i >= NB * NP) return;
    const float* f = cat + (size_t)i * CSTR + off;
    float s = 0.f;
    for (int c = 0; c < C; c += 4) {
        float4 v = *reinterpret_cast<const float4*>(f + c);
        s += v.x * v.x + v.y * v.y + v.z * v.z + v.w * v.w;
    }
    sq[i] = s;
}

// ---------------- XT4: pack layer-1 points as (x,y,z,sqnorm) — one float4 per point ----------------
__global__ void xt4_kernel(const float* __restrict__ cat, float4* __restrict__ XT4) {
    int i = blockIdx.x * blockDim.x + threadIdx.x;
    if (i >= NB * NP) return;
    const float* r = cat + (size_t)i * CSTR;
    float xx = r[0], yy = r[1], zz = r[2];
    XT4[i] = make_float4(xx, yy, zz, xx * xx + yy * yy + zz * zz);
}

// ---------------- selection core v2: top-2 cache + value-only butterfly + ballot ----------------
__device__ __forceinline__ void select_top20(float (&d)[32], int jbase, int lane,
                                             int* __restrict__ out) {
    unsigned sel = 0;
    float m1 = -INFINITY, m2 = -INFINITY;
    int j1 = 0, j2 = 0;
    #pragma unroll
    for (int t = 0; t < 32; ++t) {
        float v = d[t];
        if (v > m1) { m2 = m1; j2 = j1; m1 = v; j1 = t; }
        else if (v > m2) { m2 = v; j2 = t; }
    }
    bool dirty = false;
    for (int k = 0; k < KNN; ++k) {
        float bv = m1;
        #pragma unroll
        for (int s = 32; s; s >>= 1) bv = fmaxf(bv, __shfl_xor(bv, s));
        unsigned long long m = __ballot(m1 == bv);
        int wl = __ffsll(m) - 1;               // lowest lane holding the max
        int bj = __shfl(jbase + j1, wl);
        if (lane == 0) out[k] = bj;
        if (lane == wl) {
            sel |= 1u << j1;
            if (!dirty) {
                m1 = m2; j1 = j2; dirty = true;
            } else {
                m1 = -INFINITY; m2 = -INFINITY; j1 = 0; j2 = 0;
                #pragma unroll
                for (int t = 0; t < 32; ++t) {
                    float v = (sel & (1u << t)) ? -INFINITY : d[t];
                    if (v > m1) { m2 = m1; j2 = j1; m1 = v; j1 = t; }
                    else if (v > m2) { m2 = v; j2 = t; }
                }
                dirty = false;
            }
        }
    }
}

// ---------------- selection core v3: TWO queries per wave (knn1 only: shared loads) ----------------
__device__ __forceinline__ void select_top20_x2(float (&dA)[32], float (&dB)[32],
                                                int jbase, int lane,
                                                int* __restrict__ outA,
                                                int* __restrict__ outB) {
    unsigned selA = 0, selB = 0;
    float m1A = -INFINITY, m2A = -INFINITY, m1B = -INFINITY, m2B = -INFINITY;
    int j1A = 0, j2A = 0, j1B = 0, j2B = 0;
    #pragma unroll
    for (int t = 0; t < 32; ++t) {
        float vA = dA[t], vB = dB[t];
        if (vA > m1A) { m2A = m1A; j2A = j1A; m1A = vA; j1A = t; }
        else if (vA > m2A) { m2A = vA; j2A = t; }
        if (vB > m1B) { m2B = m1B; j2B = j1B; m1B = vB; j1B = t; }
        else if (vB > m2B) { m2B = vB; j2B = t; }
    }
    bool dirtyA = false, dirtyB = false;
    for (int k = 0; k < KNN; ++k) {
        float bvA = m1A, bvB = m1B;
        #pragma unroll
        for (int s = 32; s; s >>= 1) {
            bvA = fmaxf(bvA, __shfl_xor(bvA, s));
            bvB = fmaxf(bvB, __shfl_xor(bvB, s));
        }
        unsigned long long mA = __ballot(m1A == bvA);
        unsigned long long mB = __ballot(m1B == bvB);
        int wlA = __ffsll(mA) - 1, wlB = __ffsll(mB) - 1;
        int bjA = __shfl(jbase + j1A, wlA);
        int bjB = __shfl(jbase + j1B, wlB);
        if (lane == 0) { outA[k] = bjA; outB[k] = bjB; }
        if (lane == wlA) {
            selA |= 1u << j1A;
            if (!dirtyA) { m1A = m2A; j1A = j2A; dirtyA = true; }
            else {
                m1A = -INFINITY; m2A = -INFINITY; j1A = 0; j2A = 0;
                #pragma unroll
                for (int t = 0; t < 32; ++t) {
                    float v = (selA & (1u << t)) ? -INFINITY : dA[t];
                    if (v > m1A) { m2A = m1A; j2A = j1A; m1A = v; j1A = t; }
                    else if (v > m2A) { m2A = v; j2A = t; }
                }
                dirtyA = false;
            }
        }
        if (lane == wlB) {
            selB |= 1u << j1B;
            if (!dirtyB) { m1B = m2B; j1B = j2B; dirtyB = true; }
            else {
                m1B = -INFINITY; m2B = -INFINITY; j1B = 0; j2B = 0;
                #pragma unroll
                for (int t = 0; t < 32; ++t) {
                    float v = (selB & (1u << t)) ? -INFINITY : dB[t];
                    if (v > m1B) { m2B = m1B; j2B = j1B; m1B = v; j1B = t; }
                    else if (v > m2B) { m2B = v; j2B = t; }
                }
                dirtyB = false;
            }
        }
    }
}

// ---------------- layer-1 KNN: one wave per TWO queries, shared candidate loads ----------------
__global__ void __launch_bounds__(256) knn1_kernel(const float4* __restrict__ XT4,
                                                   int* __restrict__ idxout) {
    int wave = threadIdx.x >> 6, lane = threadIdx.x & 63;
    int q0 = blockIdx.x * 8 + wave * 2;     // two queries per wave, same batch
    int b = q0 >> 11, n0 = q0 & (NP - 1), n1 = n0 + 1;
    const float4* base = XT4 + (size_t)b * NP;
    float4 qa = base[n0];                   // wave-uniform -> broadcast
    float4 qb = base[n1];
    float dA[32], dB[32];
    #pragma unroll
    for (int t = 0; t < 32; ++t) {
        float4 v = base[lane * 32 + t];     // shared candidate load for both queries
        dA[t] = 2.f * (qa.x * v.x + qa.y * v.y + qa.z * v.z) - qa.w - v.w;
        dB[t] = 2.f * (qb.x * v.x + qb.y * v.y + qb.z * v.z) - qb.w - v.w;
    }
    select_top20_x2(dA, dB, lane * 32, lane,
                    idxout + (size_t)q0 * KNN, idxout + (size_t)(q0 + 1) * KNN);
}

// ---------------- XT: slice transpose cat[b][n][off+c] -> XT[bl][c][n] ----------------
template <int K>
__global__ void __launch_bounds__(256) xt_kernel(const float* __restrict__ cat, int off,
                                                 float* __restrict__ XT, int b0) {
    __shared__ float lds[64][K + 1];
    int bl = blockIdx.x;
    int b = b0 + bl;
    int n0 = blockIdx.y * 64;
    const float* src = cat + ((size_t)(b * NP + n0)) * CSTR + off;
    for (int e = threadIdx.x; e < 64 * (K / 4); e += 256) {
        int r = e / (K / 4), cg = e - r * (K / 4);
        float4 v = *reinterpret_cast<const float4*>(src + (size_t)r * CSTR + 4 * cg);
        lds[r][4 * cg + 0] = v.x; lds[r][4 * cg + 1] = v.y;
        lds[r][4 * cg + 2] = v.z; lds[r][4 * cg + 3] = v.w;
    }
    __syncthreads();
    float* dst = XT + (size_t)bl * K * NP;
    for (int e = threadIdx.x; e < 64 * K; e += 256) {
        int c = e >> 6, tn = e & 63;
        dst[(size_t)c * NP + n0 + tn] = lds[tn][c];
    }
}

// ---------------- SYMMETRIC distance GEMM: 64x64 tiles, upper-triangular pairs + mirror ----------------
template <int K>
__global__ void __launch_bounds__(256, 2)
distsym_kernel(const float* __restrict__ cat, int off,
               const float* __restrict__ sq,
               const float* __restrict__ XT,
               float* __restrict__ D, int b0) {
    constexpr int KP = K + 4;
    __shared__ float Arows[64][KP];          // K=128: 33.8 KB
    const int T = NP / 64;                   // 32 tiles
    const int NPAIR = T * (T + 1) / 2;       // 528
    int bid = blockIdx.x;
    int bl = bid / NPAIR;
    int p = bid - bl * NPAIR;
    int ti = 0, rem = p;
    while (rem >= T - ti) { rem -= T - ti; ++ti; }
    int tj = ti + rem;
    int b = b0 + bl;
    int rowbase = ti * 64, colbase = tj * 64;
    const float* src = cat + ((size_t)(b * NP + rowbase)) * CSTR + off;
    for (int e = threadIdx.x; e < 64 * (K / 4); e += 256) {
        int r = e / (K / 4), cg = e - r * (K / 4);
        *reinterpret_cast<float4*>(&Arows[r][4 * cg]) =
            *reinterpret_cast<const float4*>(src + (size_t)r * CSTR + 4 * cg);
    }
    __syncthreads();
    int tx = threadIdx.x & 15, ty = threadIdx.x >> 4;
    int r0 = ty * 4, c0 = tx * 4;
    int col = colbase + c0;
    const float* Wb = XT + (size_t)bl * K * NP + col;
    float acc[4][4];
    #pragma unroll
    for (int i = 0; i < 4; ++i)
        #pragma unroll
        for (int j = 0; j < 4; ++j) acc[i][j] = 0.f;
    float4 wbufA[4], wbufB[4];
    auto ldw = [&](float4 (&dst)[4], int cc) {
        dst[0] = *reinterpret_cast<const float4*>(Wb + (size_t)(cc + 0) * NP);
        dst[1] = *reinterpret_cast<const float4*>(Wb + (size_t)(cc + 1) * NP);
        dst[2] = *reinterpret_cast<const float4*>(Wb + (size_t)(cc + 2) * NP);
        dst[3] = *reinterpret_cast<const float4*>(Wb + (size_t)(cc + 3) * NP);
    };
    auto fmad = [&](float4 (&wv)[4], int cc) {
        #pragma unroll
        for (int i = 0; i < 4; ++i) {
            float4 a = *reinterpret_cast<const float4*>(&Arows[r0 + i][cc]);
            acc[i][0] += a.x * wv[0].x + a.y * wv[1].x + a.z * wv[2].x + a.w * wv[3].x;
            acc[i][1] += a.x * wv[0].y + a.y * wv[1].y + a.z * wv[2].y + a.w * wv[3].y;
            acc[i][2] += a.x * wv[0].z + a.y * wv[1].z + a.z * wv[2].z + a.w * wv[3].z;
            acc[i][3] += a.x * wv[0].w + a.y * wv[1].w + a.z * wv[2].w + a.w * wv[3].w;
        }
    };
    ldw(wbufA, 0);
    for (int c = 0; c < K; c += 8) {
        if (c + 4 < K) ldw(wbufB, c + 4);
        fmad(wbufA, c);
        if (c + 8 < K) ldw(wbufA, c + 8);
        if (c + 4 < K) fmad(wbufB, c + 4);
    }
    float4 sqc = *reinterpret_cast<const float4*>(&sq[(size_t)b * NP + col]);
    float4 dv[4];
    #pragma unroll
    for (int i = 0; i < 4; ++i) {
        float sqr = sq[(size_t)b * NP + rowbase + r0 + i];
        dv[i] = make_float4(2.f * acc[i][0] - sqr - sqc.x, 2.f * acc[i][1] - sqr - sqc.y,
                            2.f * acc[i][2] - sqr - sqc.z, 2.f * acc[i][3] - sqr - sqc.w);
        *reinterpret_cast<float4*>(&D[((size_t)bl * NP + rowbase + r0 + i) * NP + col]) = dv[i];
    }
    if (ti != tj) {   // mirror: D[col+j][rowbase+r0..r0+3]
        float4 mv0 = make_float4(dv[0].x, dv[1].x, dv[2].x, dv[3].x);
        float4 mv1 = make_float4(dv[0].y, dv[1].y, dv[2].y, dv[3].y);
        float4 mv2 = make_float4(dv[0].z, dv[1].z, dv[2].z, dv[3].z);
        float4 mv3 = make_float4(dv[0].w, dv[1].w, dv[2].w, dv[3].w);
        size_t mbase = ((size_t)bl * NP + colbase + c0);
        int mcol = rowbase + r0;
        *reinterpret_cast<float4*>(&D[(mbase + 0) * NP + mcol]) = mv0;
        *reinterpret_cast<float4*>(&D[(mbase + 1) * NP + mcol]) = mv1;
        *reinterpret_cast<float4*>(&D[(mbase + 2) * NP + mcol]) = mv2;
        *reinterpret_cast<float4*>(&D[(mbase + 3) * NP + mcol]) = mv3;
    }
}

// ---------------- top-k v5 (r25 proven): one row per wave, top-2 cache selection ----------------
__global__ void __launch_bounds__(256) topk_kernel(const float* __restrict__ D,
                                                   int* __restrict__ idxout, int b0) {
    int wave = threadIdx.x >> 6, lane = threadIdx.x & 63;
    int ql = blockIdx.x * 4 + wave;
    const float* drow = D + (size_t)ql * NP + lane * 32;
    float d[32];
    #pragma unroll
    for (int t8 = 0; t8 < 8; ++t8) {
        float4 v = *reinterpret_cast<const float4*>(drow + t8 * 4);
        d[t8 * 4 + 0] = v.x; d[t8 * 4 + 1] = v.y;
        d[t8 * 4 + 2] = v.z; d[t8 * 4 + 3] = v.w;
    }
    size_t q = (size_t)b0 * NP + ql;
    select_top20(d, lane * 32, lane, idxout + q * KNN);
}

// ---------------- YZ GEMM: NO cols/thread + double-buffered weight prefetch ----------------
template <int K, int NT, int NO>
__global__ void __launch_bounds__(NT, 2)
gemm_yz_kernel(const float* __restrict__ cat, int off,
               const float* __restrict__ W, int N2,
               float* __restrict__ YZ) {
    __shared__ float rows[16][K];
    int col = (blockIdx.y * NT + threadIdx.x) * NO;
    const float* src = cat + (size_t)blockIdx.x * 16 * CSTR + off;
    for (int e = threadIdx.x; e < 16 * (K / 4); e += NT) {
        int r = e / (K / 4), cg = e - r * (K / 4);
        *reinterpret_cast<float4*>(&rows[r][4 * cg]) =
            *reinterpret_cast<const float4*>(src + (size_t)r * CSTR + 4 * cg);
    }
    __syncthreads();
    float acc[16][NO];
    #pragma unroll
    for (int r = 0; r < 16; ++r)
        #pragma unroll
        for (int j = 0; j < NO; ++j) acc[r][j] = 0.f;
    auto ldw = [&](float (&buf)[4][NO], int cc) {
        #pragma unroll
        for (int i = 0; i < 4; ++i) {
            if constexpr (NO == 4) {
                float4 wq = *reinterpret_cast<const float4*>(&W[(size_t)(cc + i) * N2 + col]);
                buf[i][0] = wq.x; buf[i][1] = wq.y; buf[i][2] = wq.z; buf[i][3] = wq.w;
            } else if constexpr (NO == 2) {
                float2 wq = *reinterpret_cast<const float2*>(&W[(size_t)(cc + i) * N2 + col]);
                buf[i][0] = wq.x; buf[i][1] = wq.y;
            } else {
                buf[i][0] = W[(size_t)(cc + i) * N2 + col];
            }
        }
    };
    auto fmag = [&](float (&wv)[4][NO], int cc) {
        #pragma unroll
        for (int r = 0; r < 16; ++r) {
            float4 rv = *reinterpret_cast<const float4*>(&rows[r][cc]);
            #pragma unroll
            for (int j = 0; j < NO; ++j)
                acc[r][j] += rv.x * wv[0][j] + rv.y * wv[1][j] + rv.z * wv[2][j] + rv.w * wv[3][j];
        }
    };
    float wva[4][NO], wvb[4][NO];
    ldw(wva, 0);
    for (int c = 0; c < K; c += 8) {
        if (c + 4 < K) ldw(wvb, c + 4);
        fmag(wva, c);
        if (c + 8 < K) ldw(wva, c + 8);
        if (c + 4 < K) fmag(wvb, c + 4);
    }
    #pragma unroll
    for (int r = 0; r < 16; ++r) {
        float* dst = YZ + ((size_t)blockIdx.x * 16 + r) * N2 + col;
        if constexpr (NO == 4) {
            *reinterpret_cast<float4*>(dst) = make_float4(acc[r][0], acc[r][1], acc[r][2], acc[r][3]);
        } else if constexpr (NO == 2) {
            *reinterpret_cast<float2*>(dst) = make_float2(acc[r][0], acc[r][1]);
        } else {
            dst[0] = acc[r][0];
        }
    }
}

// ---------------- YZ layer-4 GEMM via bf16 MFMA (x4 feeds only the bf16 pool, no KNN) ----------------
__global__ void __launch_bounds__(256, 2)
yz4_mfma(const float* __restrict__ cat, const unsigned short* __restrict__ W4P,
         float* __restrict__ YZ) {
    __shared__ unsigned short Alds[32][296];   // 18.9 KB
    int chunk = blockIdx.x;          // 512 chunks of 32 global rows
    int cg = blockIdx.y;             // 2 col groups of 256
    for (int e = threadIdx.x; e < 32 * 72; e += 256) {
        int r = e / 72, gq = e - r * 72;
        int k = gq * 4;
        unsigned short o0 = 0, o1 = 0, o2 = 0, o3 = 0;
        if (k < 260) {
            float4 v = *reinterpret_cast<const float4*>(
                &cat[((size_t)chunk * 32 + r) * CSTR + k]);
            o0 = f2bf(v.x); o1 = f2bf(v.y); o2 = f2bf(v.z); o3 = f2bf(v.w);
        }
        *reinterpret_cast<ushort4*>(&Alds[r][k]) = make_ushort4(o0, o1, o2, o3);
    }
    __syncthreads();
    int l = threadIdx.x & 63, w = threadIdx.x >> 6;
    int ct0 = cg * 16 + w * 4;       // 32 col tiles of 16
    f32x4 acc[2][4];
    #pragma unroll
    for (int rt = 0; rt < 2; ++rt)
        #pragma unroll
        for (int t = 0; t < 4; ++t) acc[rt][t] = (f32x4){0.f, 0.f, 0.f, 0.f};
    int arow0 = (l & 15), arow1 = 16 + (l & 15);
    int koff = (l >> 4) * 8;
    for (int ks = 0; ks < 9; ++ks) {
        bf16x8 a0 = *reinterpret_cast<const bf16x8*>(&Alds[arow0][ks * 32 + koff]);
        bf16x8 a1 = *reinterpret_cast<const bf16x8*>(&Alds[arow1][ks * 32 + koff]);
        #pragma unroll
        for (int t = 0; t < 4; ++t) {
            bf16x8 bfr = *reinterpret_cast<const bf16x8*>(
                W4P + (((size_t)(ct0 + t) * 9 + ks) * 64 + l) * 8);
            acc[0][t] = __builtin_amdgcn_mfma_f32_16x16x32_bf16(a0, bfr, acc[0][t], 0, 0, 0);
            acc[1][t] = __builtin_amdgcn_mfma_f32_16x16x32_bf16(a1, bfr, acc[1][t], 0, 0, 0);
        }
    }
    #pragma unroll
    for (int rt = 0; rt < 2; ++rt)
        #pragma unroll
        for (int t = 0; t < 4; ++t) {
            int col = (ct0 + t) * 16 + (l & 15);
            #pragma unroll
            for (int jj = 0; jj < 4; ++jj) {
                int row = chunk * 32 + rt * 16 + (l >> 4) * 4 + jj;
                YZ[(size_t)row * 512 + col] = acc[rt][t][jj];
            }
        }
}

// ---------------- combine: out[p][o] = max_k leaky((Y[j_k][o] + Z[p][o])*s + b) ----------------
template <int O>
__global__ void __launch_bounds__(256) combine_kernel(const float* __restrict__ YZ, int N2,
                                                      const int* __restrict__ idx,
                                                      const float* __restrict__ g,
                                                      const float* __restrict__ bias,
                                                      float* __restrict__ cat, int outOff) {
    constexpr int PPB = 256 / O;
    int sub = threadIdx.x / O, o = threadIdx.x % O;
    int p = blockIdx.x * PPB + sub;
    int bbase = p & ~(NP - 1);
    const float bns = 1.0f / sqrtf(1.0f + 1e-5f);
    float s = g[o] * bns, bo = bias[o];
    float z = YZ[(size_t)p * N2 + O + o];
    int js[KNN];
    #pragma unroll
    for (int k = 0; k < KNN; ++k) js[k] = idx[(size_t)p * KNN + k];
    float m = -INFINITY;
    #pragma unroll
    for (int k = 0; k < KNN; ++k) {
        float y = YZ[(size_t)(bbase + js[k]) * N2 + o];
        m = fmaxf(m, leaky((y + z) * s + bo));
    }
    cat[(size_t)p * CSTR + outOff + o] = m;
}

// ---------------- fused W5 matmul + pool, v12: bf16 MFMA 16x16x32 (proven r20) ----------------
__global__ void __launch_bounds__(256, 2)
pool_w5_mfma(const float* __restrict__ cat, const unsigned short* __restrict__ W5P,
             const float* __restrict__ g5, const float* __restrict__ b5,
             float* __restrict__ pmax, float* __restrict__ psum) {
    __shared__ unsigned short Alds[32][552];   // 35.3 KB
    int b = blockIdx.x >> 6, nb = blockIdx.x & 63;   // 64 chunks of 32 rows
    int cg = blockIdx.y;                              // 4 col groups of 256
    for (int e = threadIdx.x; e < 32 * 136; e += 256) {
        int r = e / 136, gq = e - r * 136;
        int k = gq * 4;
        unsigned short o0 = 0, o1 = 0, o2 = 0, o3 = 0;
        if (k < 520) {
            float4 v = *reinterpret_cast<const float4*>(
                &cat[((size_t)b * NP + nb * 32 + r) * CSTR + k]);
            o0 = f2bf(v.x); o1 = f2bf(v.y); o2 = f2bf(v.z); o3 = f2bf(v.w);
        }
        *reinterpret_cast<ushort4*>(&Alds[r][k]) = make_ushort4(o0, o1, o2, o3);
    }
    __syncthreads();
    int l = threadIdx.x & 63, w = threadIdx.x >> 6;
    int ct0 = cg * 16 + w * 4;          // global col-tile base (64 tiles of 16)
    f32x4 acc[2][4];
    #pragma unroll
    for (int rt = 0; rt < 2; ++rt)
        #pragma unroll
        for (int t = 0; t < 4; ++t) acc[rt][t] = (f32x4){0.f, 0.f, 0.f, 0.f};
    int arow0 = (l & 15), arow1 = 16 + (l & 15);
    int koff = (l >> 4) * 8;
    for (int ks = 0; ks < 17; ++ks) {
        bf16x8 a0 = *reinterpret_cast<const bf16x8*>(&Alds[arow0][ks * 32 + koff]);
        bf16x8 a1 = *reinterpret_cast<const bf16x8*>(&Alds[arow1][ks * 32 + koff]);
        #pragma unroll
        for (int t = 0; t < 4; ++t) {
            bf16x8 bfr = *reinterpret_cast<const bf16x8*>(
                W5P + (((size_t)(ct0 + t) * 17 + ks) * 64 + l) * 8);
            acc[0][t] = __builtin_amdgcn_mfma_f32_16x16x32_bf16(a0, bfr, acc[0][t], 0, 0, 0);
            acc[1][t] = __builtin_amdgcn_mfma_f32_16x16x32_bf16(a1, bfr, acc[1][t], 0, 0, 0);
        }
    }
    const float bns = 1.0f / sqrtf(1.0f + 1e-5f);
    #pragma unroll
    for (int t = 0; t < 4; ++t) {
        int col = (ct0 + t) * 16 + (l & 15);
        float gs = g5[col] * bns, bo = b5[col];
        float vmax = -INFINITY, vsum = 0.f;
        #pragma unroll
        for (int rt = 0; rt < 2; ++rt)
            #pragma unroll
            for (int jj = 0; jj < 4; ++jj) {
                float v = leaky(acc[rt][t][jj] * gs + bo);
                vmax = fmaxf(vmax, v); vsum += v;
            }
        vmax = fmaxf(vmax, __shfl_xor(vmax, 16)); vsum += __shfl_xor(vsum, 16);
        vmax = fmaxf(vmax, __shfl_xor(vmax, 32)); vsum += __shfl_xor(vsum, 32);
        if (l < 16) {
            pmax[((size_t)b * 64 + nb) * 1024 + col] = vmax;
            psum[((size_t)b * 64 + nb) * 1024 + col] = vsum;
        }
    }
}

__global__ void pool_reduce_kernel(const float* __restrict__ pmax, const float* __restrict__ psum,
                                   float* __restrict__ f0) {
    int i = blockIdx.x * blockDim.x + threadIdx.x;
    if (i >= NB * 1024) return;
    int b = i >> 10, o = i & 1023;
    float m = -INFINITY, sm = 0.f;
    for (int nc = 0; nc < 64; ++nc) {
        m = fmaxf(m, pmax[((size_t)b * 64 + nc) * 1024 + o]);
        sm += psum[((size_t)b * 64 + nc) * 1024 + o];
    }
    f0[(size_t)b * 2048 + o] = m;
    f0[(size_t)b * 2048 + 1024 + o] = sm * (1.0f / 2048.0f);
}

// ---------------- dense: one thread per (b, o), float4 dot ----------------
__global__ void dense_kernel(const float* __restrict__ in, const float* __restrict__ W,
                             const float* __restrict__ bl, const float* __restrict__ g,
                             const float* __restrict__ bb, float* __restrict__ out,
                             int In, int Out, int act) {
    int i = blockIdx.x * blockDim.x + threadIdx.x;
    if (i >= NB * Out) return;
    int b = i / Out, o = i - b * Out;
    const float* w = W + (size_t)o * In;
    const float* xv = in + (size_t)b * In;
    float acc = 0.f;
    for (int c = 0; c < In; c += 4) {
        float4 a = *reinterpret_cast<const float4*>(&xv[c]);
        float4 v = *reinterpret_cast<const float4*>(&w[c]);
        acc += a.x * v.x + a.y * v.y + a.z * v.z + a.w * v.w;
    }
    acc += bl[o];
    if (act) {
        const float bns = 1.0f / sqrtf(1.0f + 1e-5f);
        acc = leaky(acc * (g[o] * bns) + bb[o]);
    }
    out[i] = acc;
}

extern "C" void kernel_launch(void* const* d_in, const int* in_sizes, int n_in,
                              void* d_out, int out_size, void* d_ws, size_t ws_size,
                              hipStream_t stream) {
    const float* x   = (const float*)d_in[0];
    const float* W1  = (const float*)d_in[2];
    const float* W2  = (const float*)d_in[3];
    const float* W3  = (const float*)d_in[4];
    const float* W4  = (const float*)d_in[5];
    const float* W5  = (const float*)d_in[6];
    const float* Wl1 = (const float*)d_in[7];
    const float* bl1 = (const float*)d_in[8];
    const float* Wl2 = (const float*)d_in[9];
    const float* bl2 = (const float*)d_in[10];
    const float* Wl3 = (const float*)d_in[11];
    const float* bl3 = (const float*)d_in[12];
    const float* g1 = (const float*)d_in[13]; const float* b1 = (const float*)d_in[14];
    const float* g2 = (const float*)d_in[15]; const float* b2 = (const float*)d_in[16];
    const float* g3 = (const float*)d_in[17]; const float* b3 = (const float*)d_in[18];
    const float* g4 = (const float*)d_in[19]; const float* b4 = (const float*)d_in[20];
    const float* g5 = (const float*)d_in[21]; const float* b5 = (const float*)d_in[22];
    const float* g6 = (const float*)d_in[23]; const float* bb6 = (const float*)d_in[24];
    const float* g7 = (const float*)d_in[25]; const float* bb7 = (const float*)d_in[26];

    float* ws = (float*)d_ws;
    size_t off = 0;
    float* CAT = ws + off; off += (size_t)NB * NP * CSTR;
    float* SQ  = ws + off; off += NB * NP;
    int*   IDX = (int*)(ws + off); off += (size_t)NB * NP * KNN;
    float* WYZ1 = ws + off; off += 4 * 128;
    float* WYZ2 = ws + off; off += 68 * 128;
    float* WYZ3 = ws + off; off += 132 * 256;
    float* WYZ4 = ws + off; off += 260 * 512;
    float* W5T = ws + off; off += 520 * 1024;
    unsigned short* W5P = (unsigned short*)(ws + off); off += 64 * 17 * 64 * 8 / 2;
    unsigned short* W4P = (unsigned short*)(ws + off); off += 32 * 9 * 64 * 8 / 2;
    float* BIG = ws + off;                    // shared region: DMAT+XT | XT4 | YZ | pool buffers
    size_t wsfl = ws_size / 4;
    size_t avail = (wsfl > off) ? (wsfl - off) : 0;
    const size_t yzneed = (size_t)NB * NP * 512;
    int G = 1;
    for (int g = 8; g >= 1; g >>= 1) {
        size_t need = (size_t)g * NP * 2048 + (size_t)g * 128 * NP;   // DMAT + XT(K<=128)
        size_t big = (need > yzneed) ? need : yzneed;
        if (big <= avail) { G = g; break; }
    }
    float* DMAT = BIG;
    float* XT   = BIG + (size_t)G * NP * 2048;
    float4* XT4 = (float4*)BIG;               // layer-1 point pack (256 KB)
    float* YZ   = BIG;
    float* PMAX = BIG;
    float* PSUM = PMAX + (size_t)NB * 64 * 1024;
    float* F0 = PSUM + (size_t)NB * 64 * 1024;
    float* F1 = F0 + NB * 2048;
    float* F2 = F1 + NB * 512;
    (void)in_sizes; (void)n_in; (void)out_size;

    dim3 b256(256);
    const int M16 = NB * NP / 16;   // 1024 row-blocks
    const int NPAIR = (NP / 64) * (NP / 64 + 1) / 2;   // 528

    tx_kernel<<<(NB * NP + 255) / 256, b256, 0, stream>>>(x, CAT);
    buildWyz<<<(4 * 128 + 255) / 256, b256, 0, stream>>>(W1, WYZ1, 64, 3, 4);
    buildWyz<<<(68 * 128 + 255) / 256, b256, 0, stream>>>(W2, WYZ2, 64, 67, 68);
    buildWyz<<<(132 * 256 + 255) / 256, b256, 0, stream>>>(W3, WYZ3, 128, 131, 132);
    buildWyz<<<(260 * 512 + 255) / 256, b256, 0, stream>>>(W4, WYZ4, 256, 259, 260);
    transposeW5<<<(520 * 1024 + 255) / 256, b256, 0, stream>>>(W5, W5T);
    packW5B<<<(64 * 17 * 64 + 255) / 256, b256, 0, stream>>>(W5T, W5P);
    packW4B<<<(32 * 9 * 64 + 255) / 256, b256, 0, stream>>>(WYZ4, W4P);

#define RUN_KNN(KK, OFFC)                                                                   \
    do {                                                                                    \
        sqnorm_kernel<<<(NB * NP + 255) / 256, b256, 0, stream>>>(CAT, OFFC, KK, SQ);       \
        for (int b0 = 0; b0 < NB; b0 += G) {                                                \
            xt_kernel<KK><<<dim3(G, NP / 64), b256, 0, stream>>>(CAT, OFFC, XT, b0);        \
            distsym_kernel<KK><<<G * NPAIR, b256, 0, stream>>>(CAT, OFFC, SQ, XT,           \
                                                               DMAT, b0);                   \
            topk_kernel<<<G * NP / 4, b256, 0, stream>>>(DMAT, IDX, b0);                    \
        }                                                                                   \
    } while (0)

    // layer 1: register-distance KNN (zero LDS), two queries per wave
    xt4_kernel<<<(NB * NP + 255) / 256, b256, 0, stream>>>(CAT, XT4);
    knn1_kernel<<<NB * NP / 8, b256, 0, stream>>>(XT4, IDX);
    gemm_yz_kernel<4, 128, 1><<<dim3(M16, 1), 128, 0, stream>>>(CAT, 0, WYZ1, 128, YZ);
    combine_kernel<64><<<NB * NP / 4, b256, 0, stream>>>(YZ, 128, IDX, g1, b1, CAT, 4);
    // layer 2
    RUN_KNN(64, 4);
    gemm_yz_kernel<68, 128, 1><<<dim3(M16, 1), 128, 0, stream>>>(CAT, 0, WYZ2, 128, YZ);
    combine_kernel<64><<<NB * NP / 4, b256, 0, stream>>>(YZ, 128, IDX, g2, b2, CAT, 68);
    // layer 3
    RUN_KNN(64, 68);
    gemm_yz_kernel<132, 128, 2><<<dim3(M16, 1), 128, 0, stream>>>(CAT, 0, WYZ3, 256, YZ);
    combine_kernel<128><<<NB * NP / 2, b256, 0, stream>>>(YZ, 256, IDX, g3, b3, CAT, 132);
    // layer 4: KNN exact f32 (symmetric); YZ GEMM via bf16 MFMA
    RUN_KNN(128, 132);
    yz4_mfma<<<dim3(NB * NP / 32, 2), b256, 0, stream>>>(CAT, W4P, YZ);
    combine_kernel<256><<<NB * NP, b256, 0, stream>>>(YZ, 512, IDX, g4, b4, CAT, 260);
#undef RUN_KNN

    // W5 (bf16 MFMA) + bn + leaky + global max/mean pool
    pool_w5_mfma<<<dim3(NB * 64, 4), b256, 0, stream>>>(CAT, W5P, g5, b5, PMAX, PSUM);
    pool_reduce_kernel<<<(NB * 1024 + 255) / 256, b256, 0, stream>>>(PMAX, PSUM, F0);

    // MLP head
    dense_kernel<<<(NB * 512 + 255) / 256, b256, 0, stream>>>(F0, Wl1, bl1, g6, bb6, F1, 2048, 512, 1);
    dense_kernel<<<(NB * 256 + 255) / 256, b256, 0, stream>>>(F1, Wl2, bl2, g7, bb7, F2, 512, 256, 1);
    dense_kernel<<<(NB * 40 + 255) / 256, b256, 0, stream>>>(F2, Wl3, bl3, nullptr, nullptr,
                                                             (float*)d_out, 256, 40, 0);
}